// Round 2
// baseline (1367.431 us; speedup 1.0000x reference)
//
#include <hip/hip_runtime.h>
#include <stdint.h>

#define N_TOK 131072
#define KC    512
#define DIM   128
#define GRID  2048
#define ITERS 4     /* GRID * ITERS * 16 tokens = N_TOK */
#define LOGK  6.2383246250395075f
#define CLIP_HI 0.99999988079071044921875f  /* fp32(float64(1.0-1e-7)) */
#define CLIP_LO 1.17549435e-38f
#define NLN2x2  -1.3862943611198906f        /* -2*ln2 */

typedef float  f32x4 __attribute__((ext_vector_type(4)));
typedef short  s16x8 __attribute__((ext_vector_type(8)));

__device__ __forceinline__ unsigned short f2bf(float f) {
  unsigned int b = __float_as_uint(f);
  b = b + 0x7FFFu + ((b >> 16) & 1u);   // RNE to bf16
  return (unsigned short)(b >> 16);
}

// Compact precise ln(u) for u in [FLT_MIN, 1): branchless, ~12 inst.
// Mantissa shifted into [sqrt(1/2), sqrt(2)) so u~1 has NO cancellation
// (the case hw v_log gets wrong). atanh series: |s|<=0.1716, deg-9 => ~1e-7 rel.
__device__ __forceinline__ float prec_ln(float u) {
  int i = __float_as_int(u);
  int k = (i - 0x3F3504F3) >> 23;                  // 0x3F3504F3 = bits(sqrt(0.5))
  float m = __int_as_float(i - (k << 23));         // [sqrt(1/2), sqrt(2))
  float s  = (m - 1.0f) * __builtin_amdgcn_rcpf(m + 1.0f);  // m-1 exact (Sterbenz)
  float s2 = s * s;
  float p  = fmaf(fmaf(fmaf(0.22222222f, s2, 0.28571429f), s2, 0.4f), s2, 0.66666667f);
  return fmaf((float)k, 0.69314718f, fmaf(s * s2, p, 2.0f * s));
}

// ---- prep: permuted code layout. Original code k sits at position
// j = (k&31)*16 + (k>>5)  ->  j = nt*16+c0 maps to orig code c0*32+nt,
// so each lane owns consecutive original codes (float4 U loads / enc stores).
__global__ void prep_kernel(const float* __restrict__ emb,
                            unsigned short* __restrict__ E_hi,
                            unsigned short* __restrict__ ET_hi,
                            float* __restrict__ normE) {
  int k = blockIdx.x;    // 512
  int d = threadIdx.x;   // 128
  int j = ((k & 31) << 4) | (k >> 5);
  float v = emb[k * DIM + d];
  unsigned short h = f2bf(v);
  E_hi[j * DIM + d]  = h;
  ET_hi[d * KC + j]  = h;
  __shared__ float red[128];
  red[d] = v * v;
  __syncthreads();
  for (int s = 64; s > 0; s >>= 1) { if (d < s) red[d] += red[d + s]; __syncthreads(); }
  if (d == 0) normE[j] = red[0];
}

// ---- main fused kernel: 128 threads (2 waves), 16 tokens per group,
// grid-stride over ITERS groups. Wave w owns code-positions j in [w*256,w*256+256).
__global__ __launch_bounds__(128, 4) void vq_main(
    const float* __restrict__ X, const float* __restrict__ U,
    const unsigned short* __restrict__ E_hi, const unsigned short* __restrict__ ET_hi,
    const float* __restrict__ normE,
    float* __restrict__ out_q, float* __restrict__ out_enc,
    float* __restrict__ avgp_rep, float* __restrict__ kl_rep)
{
  const int tid  = threadIdx.x;
  const int w    = tid >> 6;        // wave id 0..1 (code-half)
  const int lane = tid & 63;
  const int q    = lane >> 4;       // quad 0..3
  const int c0   = lane & 15;

  __shared__ float avgp[KC];
  __shared__ float xs[5][2][16];               // {m1,Z1,W,m2,Z2}[wave][row]
  __shared__ unsigned short encT[16][520];     // 16 tokens x 512 j-cols bf16, +8 pad

  for (int i = tid; i < KC; i += 128) avgp[i] = 0.f;
  float kl_sum = 0.f;

  for (int it = 0; it < ITERS; ++it) {
    const int wg = blockIdx.x + it * GRID;
    const int rowbase = wg * 16;

    // =============== Phase A: S = X * E^T (bf16 MFMA), l = 2S - ||e||^2 ========
    s16x8 afrag[4];
    {
      const float* xrow = X + (size_t)(rowbase + c0) * DIM;  // A: token = lane&15
      #pragma unroll
      for (int db = 0; db < 4; db++) {
        const float4 v0 = *reinterpret_cast<const float4*>(xrow + db * 32 + q * 8);
        const float4 v1 = *reinterpret_cast<const float4*>(xrow + db * 32 + q * 8 + 4);
        s16x8 u8;
        u8[0] = (short)f2bf(v0.x); u8[1] = (short)f2bf(v0.y);
        u8[2] = (short)f2bf(v0.z); u8[3] = (short)f2bf(v0.w);
        u8[4] = (short)f2bf(v1.x); u8[5] = (short)f2bf(v1.y);
        u8[6] = (short)f2bf(v1.z); u8[7] = (short)f2bf(v1.w);
        afrag[db] = u8;
      }
    }

    f32x4 acc[16];   // j-col = (w*16+nt)*16+c0 (orig code c0*32+w*16+nt), row = q*4+reg
    #pragma unroll
    for (int nt = 0; nt < 16; nt++) {
      f32x4 a = {0.f, 0.f, 0.f, 0.f};
      #pragma unroll
      for (int db = 0; db < 4; db++) {
        s16x8 b = *reinterpret_cast<const s16x8*>(
            E_hi + (size_t)((w * 16 + nt) * 16 + c0) * DIM + db * 32 + q * 8);
        a = __builtin_amdgcn_mfma_f32_16x16x32_bf16(afrag[db], b, a, 0, 0, 0);
      }
      acc[nt] = a;
    }
    #pragma unroll
    for (int nt = 0; nt < 16; nt++) {
      float ne = normE[(w * 16 + nt) * 16 + c0];
      acc[nt] = acc[nt] * 2.f - ne;   // logits (row-shifted; softmax-invariant)
    }

    // =============== Phase B: cross-wave softmax stats, KL, gumbel, enc ========
    // Stage A: local max per row
    {
      #pragma unroll
      for (int r = 0; r < 4; r++) {
        float m = acc[0][r];
        #pragma unroll
        for (int nt = 1; nt < 16; nt++) m = fmaxf(m, acc[nt][r]);
        #pragma unroll
        for (int mm = 1; mm <= 8; mm <<= 1) m = fmaxf(m, __shfl_xor(m, mm));
        if (c0 == 0) xs[0][w][q * 4 + r] = m;
      }
    }
    __syncthreads();

    // Stage B: Z1, W with global max
    {
      #pragma unroll
      for (int r = 0; r < 4; r++) {
        float m1g = fmaxf(xs[0][0][q * 4 + r], xs[0][1][q * 4 + r]);
        float Z = 0.f, W = 0.f;
        #pragma unroll
        for (int nt = 0; nt < 16; nt++) {
          float dd = acc[nt][r] - m1g;
          float e  = __expf(dd);
          Z += e; W = fmaf(e, dd, W);
        }
        #pragma unroll
        for (int mm = 1; mm <= 8; mm <<= 1) { Z += __shfl_xor(Z, mm); W += __shfl_xor(W, mm); }
        if (c0 == 0) { xs[1][w][q * 4 + r] = Z; xs[2][w][q * 4 + r] = W; }
      }
    }
    __syncthreads();

    // KL for this group's 16 rows (accumulate in register, flush once at end)
    if (tid == 0) {
      float kl = 0.f;
      for (int rr = 0; rr < 16; rr++) {
        float Z  = xs[1][0][rr] + xs[1][1][rr];
        float Wv = xs[2][0][rr] + xs[2][1][rr];
        kl += Wv / Z - logf(Z) + LOGK;
      }
      kl_sum += kl;
    }

    // Stage C: gumbel via compact logs (float4 U loads; lane's codes consecutive)
    {
      #pragma unroll
      for (int r = 0; r < 4; r++) {
        const float* urow = U + (size_t)(rowbase + q * 4 + r) * KC + c0 * 32 + w * 16;
        float m2 = -3.4e38f;
        #pragma unroll
        for (int tt = 0; tt < 4; tt++) {
          float4 u4 = *reinterpret_cast<const float4*>(urow + 4 * tt);
          #pragma unroll
          for (int j = 0; j < 4; j++) {
            float uv = (&u4.x)[j];
            uv = fminf(fmaxf(uv, CLIP_LO), CLIP_HI);
            float t  = -prec_ln(uv);              // -ln u, precise near u~1
            float g2 = NLN2x2 * __log2f(t);       // 2*gumbel; hw log safe here
            float y  = fmaf(2.0f, acc[4 * tt + j][r], g2);
            acc[4 * tt + j][r] = y;
            m2 = fmaxf(m2, y);
          }
        }
        #pragma unroll
        for (int mm = 1; mm <= 8; mm <<= 1) m2 = fmaxf(m2, __shfl_xor(m2, mm));
        if (c0 == 0) xs[3][w][q * 4 + r] = m2;
      }
    }
    __syncthreads();

    // Stage D: p = exp(y - m2g), Z2
    {
      #pragma unroll
      for (int r = 0; r < 4; r++) {
        float m2g = fmaxf(xs[3][0][q * 4 + r], xs[3][1][q * 4 + r]);
        float Z2 = 0.f;
        #pragma unroll
        for (int nt = 0; nt < 16; nt++) {
          float p = __expf(acc[nt][r] - m2g);
          acc[nt][r] = p;
          Z2 += p;
        }
        #pragma unroll
        for (int mm = 1; mm <= 8; mm <<= 1) Z2 += __shfl_xor(Z2, mm);
        if (c0 == 0) xs[4][w][q * 4 + r] = Z2;
      }
    }
    __syncthreads();

    // Stage E: enc = p/Z2 -> float4 global stores + bf16 encT + avg accumulation
    {
      float rzv[4];
      #pragma unroll
      for (int r = 0; r < 4; r++) rzv[r] = 1.0f / (xs[4][0][q * 4 + r] + xs[4][1][q * 4 + r]);

      float avg_acc[16];
      #pragma unroll
      for (int nt = 0; nt < 16; nt++) avg_acc[nt] = 0.f;

      #pragma unroll
      for (int r = 0; r < 4; r++) {
        float* erow = out_enc + (size_t)(rowbase + q * 4 + r) * KC + c0 * 32 + w * 16;
        #pragma unroll
        for (int tt = 0; tt < 4; tt++) {
          float4 ev;
          #pragma unroll
          for (int j = 0; j < 4; j++) {
            float enc = acc[4 * tt + j][r] * rzv[r];
            (&ev.x)[j] = enc;
            avg_acc[4 * tt + j] += enc;
          }
          *reinterpret_cast<float4*>(erow + 4 * tt) = ev;
          #pragma unroll
          for (int j = 0; j < 4; j++) {
            float enc = (&ev.x)[j];
            float pv = __shfl_xor(enc, 1);   // pair (c0,c0+1) -> one dword LDS write
            if (!(lane & 1)) {
              unsigned int pk = (unsigned int)f2bf(enc) | ((unsigned int)f2bf(pv) << 16);
              *reinterpret_cast<unsigned int*>(
                  &encT[q * 4 + r][(w * 16 + 4 * tt + j) * 16 + c0]) = pk;
            }
          }
        }
      }

      // avg_probs in PERMUTED j-space (perplexity is permutation-invariant):
      // index (w*16+nt)*16+lane -> stride-16 across lanes 0..15, conflict-free.
      #pragma unroll
      for (int nt = 0; nt < 16; nt++) {
        float v = avg_acc[nt];
        v += __shfl_xor(v, 16);
        v += __shfl_xor(v, 32);
        if (lane < 16) avgp[(w * 16 + nt) * 16 + lane] += v;
      }
    }
    __syncthreads();

    // =============== Phase C: quantized = Enc * E (bf16 MFMA) ==================
    f32x4 accq[4];
    #pragma unroll
    for (int n2 = 0; n2 < 4; n2++) accq[n2] = {0.f, 0.f, 0.f, 0.f};
    #pragma unroll
    for (int kb = 0; kb < 16; kb++) {
      s16x8 af = *reinterpret_cast<const s16x8*>(&encT[c0][kb * 32 + q * 8]);
      #pragma unroll
      for (int n2 = 0; n2 < 4; n2++) {
        s16x8 b = *reinterpret_cast<const s16x8*>(
            ET_hi + (size_t)(w * 64 + n2 * 16 + c0) * KC + kb * 32 + q * 8);
        accq[n2] = __builtin_amdgcn_mfma_f32_16x16x32_bf16(af, b, accq[n2], 0, 0, 0);
      }
    }
    #pragma unroll
    for (int n2 = 0; n2 < 4; n2++) {
      #pragma unroll
      for (int r = 0; r < 4; r++) {
        int grow = rowbase + q * 4 + r;
        out_q[(size_t)grow * DIM + w * 64 + n2 * 16 + c0] = accq[n2][r];
      }
    }
    // next iteration's encT writes are separated by >=2 barriers (stages A-D)
  }

  // =============== flush block-level reductions once ===========================
  for (int i = tid; i < KC; i += 128)
    atomicAdd(&avgp_rep[(size_t)(blockIdx.x & 31) * KC + i], avgp[i]);
  if (tid == 0) atomicAdd(&kl_rep[blockIdx.x & 31], kl_sum);
}

// ---- finalize: perplexity + KL scalars
__global__ void finalize_kernel(const float* __restrict__ avgp_rep,
                                const float* __restrict__ kl_rep,
                                float* __restrict__ d_out) {
  __shared__ float red[512];
  int t = threadIdx.x;   // 512
  float s = 0.f;
  for (int rsl = 0; rsl < 32; rsl++) s += avgp_rep[rsl * KC + t];
  float avg = s * (1.0f / (float)N_TOK);
  red[t] = avg * logf(avg + 1e-10f);
  __syncthreads();
  for (int st = 256; st > 0; st >>= 1) { if (t < st) red[t] += red[t + st]; __syncthreads(); }
  if (t == 0) {
    d_out[1 + (size_t)N_TOK * DIM] = __expf(-red[0]);   // perplexity
    float kl = 0.f;
    for (int i2 = 0; i2 < 32; i2++) kl += kl_rep[i2];
    d_out[0] = kl * (1.0f / (float)KC);                 // KL
  }
}

extern "C" void kernel_launch(void* const* d_in, const int* in_sizes, int n_in,
                              void* d_out, int out_size, void* d_ws, size_t ws_size,
                              hipStream_t stream) {
  const float* X = (const float*)d_in[0];
  const float* U = (const float*)d_in[1];
  const float* E = (const float*)d_in[2];
  float* out = (float*)d_out;

  char* ws = (char*)d_ws;
  unsigned short* E_hi   = (unsigned short*)(ws);            // 512*128*2 = 131072
  unsigned short* ET_hi  = (unsigned short*)(ws + 131072);   // 128*512*2 = 131072
  float*          normE  = (float*)(ws + 262144);            // 2048
  float*          avgp_r = (float*)(ws + 264192);            // 32*512*4 = 65536
  float*          kl_r   = (float*)(ws + 329728);            // 128

  hipMemsetAsync(ws + 264192, 0, 65536 + 128, stream);
  prep_kernel<<<512, 128, 0, stream>>>(E, E_hi, ET_hi, normE);
  vq_main<<<GRID, 128, 0, stream>>>(X, U, E_hi, ET_hi, normE,
                                    out + 1,
                                    out + 1 + (size_t)N_TOK * DIM + 1,
                                    avgp_r, kl_r);
  finalize_kernel<<<1, 512, 0, stream>>>(avgp_r, kl_r, out);
}

// Round 3
// 693.996 us; speedup vs baseline: 1.9704x; 1.9704x over previous
//
#include <hip/hip_runtime.h>
#include <stdint.h>

#define N_TOK 131072
#define KC    512
#define DIM   128
#define LOGK  6.2383246250395075f
#define CLIP_HI 0.99999988079071044921875f  /* fp32(float64(1.0-1e-7)) */
#define CLIP_LO 1.17549435e-38f
#define NLN2x2  -1.3862943611198906f        /* -2*ln2 */

typedef float  f32x4 __attribute__((ext_vector_type(4)));
typedef short  s16x8 __attribute__((ext_vector_type(8)));

__device__ __forceinline__ unsigned short f2bf(float f) {
  unsigned int b = __float_as_uint(f);
  b = b + 0x7FFFu + ((b >> 16) & 1u);   // RNE to bf16
  return (unsigned short)(b >> 16);
}

// Compact precise ln(u) for u in [FLT_MIN, 1): branchless, ~12 inst.
// Mantissa shifted into [sqrt(1/2), sqrt(2)) so u~1 has NO cancellation.
__device__ __forceinline__ float prec_ln(float u) {
  int i = __float_as_int(u);
  int k = (i - 0x3F3504F3) >> 23;                  // 0x3F3504F3 = bits(sqrt(0.5))
  float m = __int_as_float(i - (k << 23));         // [sqrt(1/2), sqrt(2))
  float s  = (m - 1.0f) * __builtin_amdgcn_rcpf(m + 1.0f);  // m-1 exact (Sterbenz)
  float s2 = s * s;
  float p  = fmaf(fmaf(fmaf(0.22222222f, s2, 0.28571429f), s2, 0.4f), s2, 0.66666667f);
  return fmaf((float)k, 0.69314718f, fmaf(s * s2, p, 2.0f * s));
}

// ---- prep: fragment-major bf16 tables so every MFMA B-fragment load in vq_main
// is 64 lanes x 16B CONTIGUOUS (1KB burst), not a 16-row gather.
// Permuted code position j = (k&31)*16 + (k>>5)  (orig code of j = c0*32 + nt,
// so each lane owns consecutive original codes for float4 U loads / enc stores).
// EF  [w][nt][db][lane=q*16+c0][8]: E row (w*16+nt)*16+c0, cols db*32+q*8..+8
// ETF [w2][n2][kb][lane=q*16+c0][8]: dim w2*64+n2*16+c0, j-cols kb*32+q*8..+8
__global__ void prep_kernel(const float* __restrict__ emb,
                            unsigned short* __restrict__ EF,
                            unsigned short* __restrict__ ETF,
                            float* __restrict__ normE) {
  int k = blockIdx.x;    // 512
  int d = threadIdx.x;   // 128
  int j = ((k & 31) << 4) | (k >> 5);
  float v = emb[k * DIM + d];
  unsigned short h = f2bf(v);
  {
    int w  = j >> 8, nt = (j >> 4) & 15, c0 = j & 15;
    int db = d >> 5, q = (d >> 3) & 3, e = d & 7;
    EF[((((size_t)(w * 16 + nt) * 4 + db) * 64) + (q * 16 + c0)) * 8 + e] = h;
  }
  {
    int w2 = d >> 6, n2 = (d >> 4) & 3, c0 = d & 15;
    int kb = j >> 5, q = (j >> 3) & 3, e = j & 7;
    ETF[((((size_t)(w2 * 4 + n2) * 16 + kb) * 64) + (q * 16 + c0)) * 8 + e] = h;
  }
  __shared__ float red[128];
  red[d] = v * v;
  __syncthreads();
  for (int s = 64; s > 0; s >>= 1) { if (d < s) red[d] += red[d + s]; __syncthreads(); }
  if (d == 0) normE[j] = red[0];
}

// ---- main fused kernel: 128 threads (2 waves), 16 tokens per block.
// Wave w owns code-positions j in [w*256, w*256+256). Only TWO barriers/block.
__global__ __launch_bounds__(128, 4) void vq_main(
    const float* __restrict__ X, const float* __restrict__ U,
    const unsigned short* __restrict__ EF, const unsigned short* __restrict__ ETF,
    const float* __restrict__ normE,
    float* __restrict__ out_q, float* __restrict__ out_enc,
    float* __restrict__ avgp_rep, float* __restrict__ kl_rep)
{
  const int tid  = threadIdx.x;
  const int w    = tid >> 6;        // wave id 0..1 (code-half)
  const int lane = tid & 63;
  const int q    = lane >> 4;       // quad 0..3
  const int c0   = lane & 15;
  const int wg   = blockIdx.x;
  const int rowbase = wg * 16;      // block's 16 token rows

  __shared__ float xs[5][2][16];               // {m1,Z1,W,m2,Z2}[wave][row]
  __shared__ unsigned short encT[16][520];     // 16 tokens x 512 j-cols bf16, +8 pad

  // ================= Phase A: S = X * E^T (bf16 MFMA), l = 2S - ||e||^2 ========
  s16x8 afrag[4];
  {
    const float* xrow = X + (size_t)(rowbase + c0) * DIM;  // A: token = lane&15
    #pragma unroll
    for (int db = 0; db < 4; db++) {
      const float4 v0 = *reinterpret_cast<const float4*>(xrow + db * 32 + q * 8);
      const float4 v1 = *reinterpret_cast<const float4*>(xrow + db * 32 + q * 8 + 4);
      s16x8 u8;
      u8[0] = (short)f2bf(v0.x); u8[1] = (short)f2bf(v0.y);
      u8[2] = (short)f2bf(v0.z); u8[3] = (short)f2bf(v0.w);
      u8[4] = (short)f2bf(v1.x); u8[5] = (short)f2bf(v1.y);
      u8[6] = (short)f2bf(v1.z); u8[7] = (short)f2bf(v1.w);
      afrag[db] = u8;
    }
  }

  f32x4 acc[16];   // j-col = (w*16+nt)*16+c0 (orig code c0*32+w*16+nt), row = q*4+reg
  const unsigned short* efw = EF + (size_t)w * (16 * 4 * 64 * 8);
  #pragma unroll
  for (int nt = 0; nt < 16; nt++) {
    f32x4 a = {0.f, 0.f, 0.f, 0.f};
    #pragma unroll
    for (int db = 0; db < 4; db++) {
      s16x8 b = *reinterpret_cast<const s16x8*>(efw + ((size_t)(nt * 4 + db) * 64 + lane) * 8);
      a = __builtin_amdgcn_mfma_f32_16x16x32_bf16(afrag[db], b, a, 0, 0, 0);
    }
    acc[nt] = a;
  }
  #pragma unroll
  for (int nt = 0; nt < 16; nt++) {
    float ne = normE[(w * 16 + nt) * 16 + c0];
    acc[nt] = acc[nt] * 2.f - ne;   // logits (row-shifted; softmax-invariant)
  }

  // ====== Phase B: per-wave stats with LOCAL max (no barrier), then one merge ==
  #pragma unroll
  for (int r = 0; r < 4; r++) {
    const int rr = q * 4 + r;
    // local max
    float m = acc[0][r];
    #pragma unroll
    for (int nt = 1; nt < 16; nt++) m = fmaxf(m, acc[nt][r]);
    #pragma unroll
    for (int mm = 1; mm <= 8; mm <<= 1) m = fmaxf(m, __shfl_xor(m, mm));
    // Z, W with local max
    float Z = 0.f, W = 0.f;
    #pragma unroll
    for (int nt = 0; nt < 16; nt++) {
      float dd = acc[nt][r] - m;
      float e  = __expf(dd);
      Z += e; W = fmaf(e, dd, W);
    }
    #pragma unroll
    for (int mm = 1; mm <= 8; mm <<= 1) { Z += __shfl_xor(Z, mm); W += __shfl_xor(W, mm); }
    if (c0 == 0) { xs[0][w][rr] = m; xs[1][w][rr] = Z; xs[2][w][rr] = W; }

    // gumbel: y = 2*(l+g) overwrites acc; local m2
    const float* urow = U + (size_t)(rowbase + rr) * KC + c0 * 32 + w * 16;
    float m2 = -3.4e38f;
    #pragma unroll
    for (int tt = 0; tt < 4; tt++) {
      float4 u4 = *reinterpret_cast<const float4*>(urow + 4 * tt);
      #pragma unroll
      for (int jj = 0; jj < 4; jj++) {
        float uv = (&u4.x)[jj];
        uv = fminf(fmaxf(uv, CLIP_LO), CLIP_HI);
        float t  = -prec_ln(uv);              // -ln u, precise near u~1
        float g2 = NLN2x2 * __log2f(t);       // 2*gumbel; hw log safe here
        float y  = fmaf(2.0f, acc[4 * tt + jj][r], g2);
        acc[4 * tt + jj][r] = y;
        m2 = fmaxf(m2, y);
      }
    }
    #pragma unroll
    for (int mm = 1; mm <= 8; mm <<= 1) m2 = fmaxf(m2, __shfl_xor(m2, mm));
    // p = exp(y - m2_local), Z2
    float Z2 = 0.f;
    #pragma unroll
    for (int nt = 0; nt < 16; nt++) {
      float p = __expf(acc[nt][r] - m2);
      acc[nt][r] = p;
      Z2 += p;
    }
    #pragma unroll
    for (int mm = 1; mm <= 8; mm <<= 1) Z2 += __shfl_xor(Z2, mm);
    if (c0 == 0) { xs[3][w][rr] = m2; xs[4][w][rr] = Z2; }
  }
  __syncthreads();   // ---- the single stats barrier ----

  // KL via LSE merge (lanes 0..15 of wave 0; one row each)
  if (tid < 16) {
    float m0 = xs[0][0][tid], m1 = xs[0][1][tid];
    float mg = fmaxf(m0, m1);
    float s0 = __expf(m0 - mg), s1 = __expf(m1 - mg);
    float Z  = fmaf(s0, xs[1][0][tid], s1 * xs[1][1][tid]);
    float Wv = s0 * fmaf(m0 - mg, xs[1][0][tid], xs[2][0][tid])
             + s1 * fmaf(m1 - mg, xs[1][1][tid], xs[2][1][tid]);
    float kl = Wv / Z - prec_ln(Z) + LOGK;
    #pragma unroll
    for (int mm = 1; mm <= 8; mm <<= 1) kl += __shfl_xor(kl, mm);
    if (tid == 0) atomicAdd(&kl_rep[wg & 31], kl);
  }

  // per-row enc scale for THIS wave: rz = exp(m2_w - m2g) / Z2g
  float rzv[4];
  #pragma unroll
  for (int r = 0; r < 4; r++) {
    const int rr = q * 4 + r;
    float m20 = xs[3][0][rr], m21 = xs[3][1][rr];
    float m2g = fmaxf(m20, m21);
    float Z2g = fmaf(__expf(m20 - m2g), xs[4][0][rr], __expf(m21 - m2g) * xs[4][1][rr]);
    float mw  = w ? m21 : m20;
    rzv[r] = __expf(mw - m2g) * __builtin_amdgcn_rcpf(Z2g);
  }

  // ====== Stage E: enc = p*rz -> float4 stores + bf16 encT + avg accumulation ==
  {
    float avg_acc[16];
    #pragma unroll
    for (int nt = 0; nt < 16; nt++) avg_acc[nt] = 0.f;

    #pragma unroll
    for (int r = 0; r < 4; r++) {
      float* erow = out_enc + (size_t)(rowbase + q * 4 + r) * KC + c0 * 32 + w * 16;
      #pragma unroll
      for (int tt = 0; tt < 4; tt++) {
        float4 ev;
        #pragma unroll
        for (int jj = 0; jj < 4; jj++) {
          float enc = acc[4 * tt + jj][r] * rzv[r];
          (&ev.x)[jj] = enc;
          avg_acc[4 * tt + jj] += enc;
        }
        *reinterpret_cast<float4*>(erow + 4 * tt) = ev;
        #pragma unroll
        for (int jj = 0; jj < 4; jj++) {
          float enc = (&ev.x)[jj];
          float pv = __shfl_xor(enc, 1);   // pair (c0,c0+1) -> one dword LDS write
          if (!(lane & 1)) {
            unsigned int pk = (unsigned int)f2bf(enc) | ((unsigned int)f2bf(pv) << 16);
            *reinterpret_cast<unsigned int*>(
                &encT[q * 4 + r][(w * 16 + 4 * tt + jj) * 16 + c0]) = pk;
          }
        }
      }
    }

    // avg_probs in PERMUTED j-space (perplexity is permutation-invariant);
    // lane is the fast index -> conflict-free, one owner per address.
    #pragma unroll
    for (int nt = 0; nt < 16; nt++) {
      float v = avg_acc[nt];
      v += __shfl_xor(v, 16);
      v += __shfl_xor(v, 32);
      if (lane < 16)
        atomicAdd(&avgp_rep[(size_t)(wg & 31) * KC + (w * 16 + nt) * 16 + lane], v);
    }
  }
  __syncthreads();   // ---- encT visible to both waves ----

  // ================= Phase C: quantized = Enc * E (bf16 MFMA) ==================
  f32x4 accq[4];
  #pragma unroll
  for (int n2 = 0; n2 < 4; n2++) accq[n2] = {0.f, 0.f, 0.f, 0.f};
  #pragma unroll
  for (int kb = 0; kb < 16; kb++) {
    s16x8 af = *reinterpret_cast<const s16x8*>(&encT[c0][kb * 32 + q * 8]);
    #pragma unroll
    for (int n2 = 0; n2 < 4; n2++) {
      s16x8 b = *reinterpret_cast<const s16x8*>(
          ETF + ((size_t)((w * 4 + n2) * 16 + kb) * 64 + lane) * 8);
      accq[n2] = __builtin_amdgcn_mfma_f32_16x16x32_bf16(af, b, accq[n2], 0, 0, 0);
    }
  }
  #pragma unroll
  for (int n2 = 0; n2 < 4; n2++) {
    #pragma unroll
    for (int r = 0; r < 4; r++) {
      int grow = rowbase + q * 4 + r;
      out_q[(size_t)grow * DIM + w * 64 + n2 * 16 + c0] = accq[n2][r];
    }
  }
}

// ---- finalize: perplexity + KL scalars
__global__ void finalize_kernel(const float* __restrict__ avgp_rep,
                                const float* __restrict__ kl_rep,
                                float* __restrict__ d_out) {
  __shared__ float red[512];
  int t = threadIdx.x;   // 512
  float s = 0.f;
  for (int rsl = 0; rsl < 32; rsl++) s += avgp_rep[rsl * KC + t];
  float avg = s * (1.0f / (float)N_TOK);
  red[t] = avg * logf(avg + 1e-10f);
  __syncthreads();
  for (int st = 256; st > 0; st >>= 1) { if (t < st) red[t] += red[t + st]; __syncthreads(); }
  if (t == 0) {
    d_out[1 + (size_t)N_TOK * DIM] = __expf(-red[0]);   // perplexity
    float kl = 0.f;
    for (int i2 = 0; i2 < 32; i2++) kl += kl_rep[i2];
    d_out[0] = kl * (1.0f / (float)KC);                 // KL
  }
}

extern "C" void kernel_launch(void* const* d_in, const int* in_sizes, int n_in,
                              void* d_out, int out_size, void* d_ws, size_t ws_size,
                              hipStream_t stream) {
  const float* X = (const float*)d_in[0];
  const float* U = (const float*)d_in[1];
  const float* E = (const float*)d_in[2];
  float* out = (float*)d_out;

  char* ws = (char*)d_ws;
  unsigned short* EF     = (unsigned short*)(ws);            // 512*128*2 = 131072
  unsigned short* ETF    = (unsigned short*)(ws + 131072);   // 128*512*2 = 131072
  float*          normE  = (float*)(ws + 262144);            // 2048
  float*          avgp_r = (float*)(ws + 264192);            // 32*512*4 = 65536
  float*          kl_r   = (float*)(ws + 329728);            // 128

  hipMemsetAsync(ws + 264192, 0, 65536 + 128, stream);
  prep_kernel<<<512, 128, 0, stream>>>(E, EF, ETF, normE);
  vq_main<<<N_TOK / 16, 128, 0, stream>>>(X, U, EF, ETF, normE,
                                          out + 1,
                                          out + 1 + (size_t)N_TOK * DIM + 1,
                                          avgp_r, kl_r);
  finalize_kernel<<<1, 512, 0, stream>>>(avgp_r, kl_r, out);
}

// Round 4
// 629.712 us; speedup vs baseline: 2.1715x; 1.1021x over previous
//
#include <hip/hip_runtime.h>
#include <stdint.h>

#define N_TOK 131072
#define KC    512
#define DIM   128
#define LOGK  6.2383246250395075f
#define CLIP_HI 0.99999988079071044921875f  /* fp32(float64(1.0-1e-7)) */
#define CLIP_LO 1.17549435e-38f
#define NLN2x2  -1.3862943611198906f        /* -2*ln2 */

typedef float  f32x4 __attribute__((ext_vector_type(4)));
typedef short  s16x8 __attribute__((ext_vector_type(8)));

__device__ __forceinline__ unsigned short f2bf(float f) {
  unsigned int b = __float_as_uint(f);
  b = b + 0x7FFFu + ((b >> 16) & 1u);   // RNE to bf16
  return (unsigned short)(b >> 16);
}

// Compact precise ln(u) for u in [FLT_MIN, 1): branchless, ~12 inst.
// Mantissa shifted into [sqrt(1/2), sqrt(2)) so u~1 has NO cancellation.
__device__ __forceinline__ float prec_ln(float u) {
  int i = __float_as_int(u);
  int k = (i - 0x3F3504F3) >> 23;                  // 0x3F3504F3 = bits(sqrt(0.5))
  float m = __int_as_float(i - (k << 23));         // [sqrt(1/2), sqrt(2))
  float s  = (m - 1.0f) * __builtin_amdgcn_rcpf(m + 1.0f);  // m-1 exact (Sterbenz)
  float s2 = s * s;
  float p  = fmaf(fmaf(fmaf(0.22222222f, s2, 0.28571429f), s2, 0.4f), s2, 0.66666667f);
  return fmaf((float)k, 0.69314718f, fmaf(s * s2, p, 2.0f * s));
}

// ---- prep: fragment-major bf16 tables + COALESCING code permutation.
// Permuted position j of original code k:  k bits [w(1)|t(2)|c0(4)|jj(2)]
//   j = (w*16 + t*4 + jj)*16 + c0
// -> in vq_main, for a U/enc access (w,tt fixed), lanes c0=0..15 hit
//    orig codes (w*4+tt)*64 + c0*4 + jj: 16 lanes x 16B CONTIGUOUS.
// EF  [w][nt][db][lane=q*16+c0][8]: E row j=(w*16+nt)*16+c0, cols db*32+q*8..+8
// ETF [w2][n2][kb][lane=q*16+c0][8]: dim w2*64+n2*16+c0, j-cols kb*32+q*8..+8
// normE2[w*256 + c0*16 + nt]: per-lane 16 contiguous norms (4 x float4).
__global__ void prep_kernel(const float* __restrict__ emb,
                            unsigned short* __restrict__ EF,
                            unsigned short* __restrict__ ETF,
                            float* __restrict__ normE2) {
  int k = blockIdx.x;    // 512
  int d = threadIdx.x;   // 128
  int wk = (k >> 8) & 1, tk = (k >> 6) & 3, ck = (k >> 2) & 15, jk = k & 3;
  int j = ((wk * 16 + tk * 4 + jk) << 4) | ck;
  float v = emb[k * DIM + d];
  unsigned short h = f2bf(v);
  {
    int w  = j >> 8, nt = (j >> 4) & 15, c0 = j & 15;
    int db = d >> 5, q = (d >> 3) & 3, e = d & 7;
    EF[((((size_t)(w * 16 + nt) * 4 + db) * 64) + (q * 16 + c0)) * 8 + e] = h;
  }
  {
    int w2 = d >> 6, n2 = (d >> 4) & 3, c0 = d & 15;
    int kb = j >> 5, q = (j >> 3) & 3, e = j & 7;
    ETF[((((size_t)(w2 * 4 + n2) * 16 + kb) * 64) + (q * 16 + c0)) * 8 + e] = h;
  }
  __shared__ float red[128];
  red[d] = v * v;
  __syncthreads();
  for (int s = 64; s > 0; s >>= 1) { if (d < s) red[d] += red[d + s]; __syncthreads(); }
  if (d == 0) normE2[(j >> 8) * 256 + (j & 15) * 16 + ((j >> 4) & 15)] = red[0];
}

// ---- main fused kernel: 128 threads (2 waves), 16 tokens per block.
// Wave w owns code-positions j in [w*256, w*256+256). Two barriers/block.
// launch_bounds(128,3): 170-reg budget so U prefetch (64 VGPR) fits unspilled.
__global__ __launch_bounds__(128, 3) void vq_main(
    const float* __restrict__ X, const float* __restrict__ U,
    const unsigned short* __restrict__ EF, const unsigned short* __restrict__ ETF,
    const float* __restrict__ normE2,
    float* __restrict__ out_q, float* __restrict__ out_enc,
    float* __restrict__ avgp_rep, float* __restrict__ kl_rep)
{
  const int tid  = threadIdx.x;
  const int w    = tid >> 6;        // wave id 0..1 (code-half)
  const int lane = tid & 63;
  const int q    = lane >> 4;       // quad 0..3
  const int c0   = lane & 15;
  const int wg   = blockIdx.x;
  const int rowbase = wg * 16;      // block's 16 token rows

  __shared__ float xs[5][2][16];               // {m1,Z1,W,m2,Z2}[wave][row]
  __shared__ unsigned short encT[16][520];     // 16 tokens x 512 j-cols bf16, +8 pad

  // ================= Phase A: S = X * E^T (bf16 MFMA), l = 2S - ||e||^2 ========
  s16x8 afrag[4];
  {
    const float* xrow = X + (size_t)(rowbase + c0) * DIM;  // A: token = lane&15
    #pragma unroll
    for (int db = 0; db < 4; db++) {
      const float4 v0 = *reinterpret_cast<const float4*>(xrow + db * 32 + q * 8);
      const float4 v1 = *reinterpret_cast<const float4*>(xrow + db * 32 + q * 8 + 4);
      s16x8 u8;
      u8[0] = (short)f2bf(v0.x); u8[1] = (short)f2bf(v0.y);
      u8[2] = (short)f2bf(v0.z); u8[3] = (short)f2bf(v0.w);
      u8[4] = (short)f2bf(v1.x); u8[5] = (short)f2bf(v1.y);
      u8[6] = (short)f2bf(v1.z); u8[7] = (short)f2bf(v1.w);
      afrag[db] = u8;
    }
  }

  f32x4 acc[16];   // j-col = (w*16+nt)*16+c0, row(token) = q*4+reg
  const unsigned short* efw = EF + (size_t)w * (16 * 4 * 64 * 8);
  #pragma unroll
  for (int nt = 0; nt < 16; nt++) {
    f32x4 a = {0.f, 0.f, 0.f, 0.f};
    #pragma unroll
    for (int db = 0; db < 4; db++) {
      s16x8 b = *reinterpret_cast<const s16x8*>(efw + ((size_t)(nt * 4 + db) * 64 + lane) * 8);
      a = __builtin_amdgcn_mfma_f32_16x16x32_bf16(afrag[db], b, a, 0, 0, 0);
    }
    acc[nt] = a;
  }

  // ---- U prefetch: all 16 float4 issued here (afrag dead; ~700cy of stats
  // VALU before first use hides L3/HBM latency with full 16-load MLP).
  // Coalesced: lanes c0=0..15 -> 16B each, contiguous 256B per quad.
  float4 ureg[4][4];
  {
    const float* ub = U + (size_t)rowbase * KC + (size_t)(w * 4) * 64 + c0 * 4;
    #pragma unroll
    for (int r = 0; r < 4; r++)
      #pragma unroll
      for (int tt = 0; tt < 4; tt++)
        ureg[r][tt] = *reinterpret_cast<const float4*>(ub + (size_t)(q * 4 + r) * KC + tt * 64);
  }

  // norms: 4 contiguous float4 per lane
  {
    const float* nb = normE2 + w * 256 + c0 * 16;
    float4 nv[4];
    #pragma unroll
    for (int i = 0; i < 4; i++) nv[i] = *reinterpret_cast<const float4*>(nb + 4 * i);
    #pragma unroll
    for (int nt = 0; nt < 16; nt++) {
      float ne = (&nv[nt >> 2].x)[nt & 3];
      acc[nt] = acc[nt] * 2.f - ne;   // logits (row-shifted; softmax-invariant)
    }
  }

  // ====== Phase B: per-wave stats with LOCAL max (no barrier), then one merge ==
  #pragma unroll
  for (int r = 0; r < 4; r++) {
    const int rr = q * 4 + r;
    // local max
    float m = acc[0][r];
    #pragma unroll
    for (int nt = 1; nt < 16; nt++) m = fmaxf(m, acc[nt][r]);
    #pragma unroll
    for (int mm = 1; mm <= 8; mm <<= 1) m = fmaxf(m, __shfl_xor(m, mm));
    // Z, W with local max
    float Z = 0.f, W = 0.f;
    #pragma unroll
    for (int nt = 0; nt < 16; nt++) {
      float dd = acc[nt][r] - m;
      float e  = __expf(dd);
      Z += e; W = fmaf(e, dd, W);
    }
    #pragma unroll
    for (int mm = 1; mm <= 8; mm <<= 1) { Z += __shfl_xor(Z, mm); W += __shfl_xor(W, mm); }
    if (c0 == 0) { xs[0][w][rr] = m; xs[1][w][rr] = Z; xs[2][w][rr] = W; }

    // gumbel from prefetched U: y = 2*(l+g) overwrites acc; local m2
    float m2 = -3.4e38f;
    #pragma unroll
    for (int tt = 0; tt < 4; tt++) {
      #pragma unroll
      for (int jj = 0; jj < 4; jj++) {
        float uv = (&ureg[r][tt].x)[jj];
        uv = fminf(fmaxf(uv, CLIP_LO), CLIP_HI);
        float t  = -prec_ln(uv);              // -ln u, precise near u~1
        float g2 = NLN2x2 * __log2f(t);       // 2*gumbel; hw log safe here
        float y  = fmaf(2.0f, acc[4 * tt + jj][r], g2);
        acc[4 * tt + jj][r] = y;
        m2 = fmaxf(m2, y);
      }
    }
    #pragma unroll
    for (int mm = 1; mm <= 8; mm <<= 1) m2 = fmaxf(m2, __shfl_xor(m2, mm));
    // p = exp(y - m2_local), Z2
    float Z2 = 0.f;
    #pragma unroll
    for (int nt = 0; nt < 16; nt++) {
      float p = __expf(acc[nt][r] - m2);
      acc[nt][r] = p;
      Z2 += p;
    }
    #pragma unroll
    for (int mm = 1; mm <= 8; mm <<= 1) Z2 += __shfl_xor(Z2, mm);
    if (c0 == 0) { xs[3][w][rr] = m2; xs[4][w][rr] = Z2; }
  }
  __syncthreads();   // ---- the single stats barrier ----

  // KL via LSE merge (lanes 0..15 of wave 0; one row each)
  if (tid < 16) {
    float m0 = xs[0][0][tid], m1 = xs[0][1][tid];
    float mg = fmaxf(m0, m1);
    float s0 = __expf(m0 - mg), s1 = __expf(m1 - mg);
    float Z  = fmaf(s0, xs[1][0][tid], s1 * xs[1][1][tid]);
    float Wv = s0 * fmaf(m0 - mg, xs[1][0][tid], xs[2][0][tid])
             + s1 * fmaf(m1 - mg, xs[1][1][tid], xs[2][1][tid]);
    float kl = Wv / Z - prec_ln(Z) + LOGK;
    #pragma unroll
    for (int mm = 1; mm <= 8; mm <<= 1) kl += __shfl_xor(kl, mm);
    if (tid == 0) atomicAdd(&kl_rep[wg & 31], kl);
  }

  // per-row enc scale for THIS wave: rz = exp(m2_w - m2g) / Z2g
  float rzv[4];
  #pragma unroll
  for (int r = 0; r < 4; r++) {
    const int rr = q * 4 + r;
    float m20 = xs[3][0][rr], m21 = xs[3][1][rr];
    float m2g = fmaxf(m20, m21);
    float Z2g = fmaf(__expf(m20 - m2g), xs[4][0][rr], __expf(m21 - m2g) * xs[4][1][rr]);
    float mw  = w ? m21 : m20;
    rzv[r] = __expf(mw - m2g) * __builtin_amdgcn_rcpf(Z2g);
  }

  // ====== Stage E: enc = p*rz -> COALESCED float4 stores + bf16 encT + avg =====
  {
    float avg_acc[16];
    #pragma unroll
    for (int nt = 0; nt < 16; nt++) avg_acc[nt] = 0.f;

    #pragma unroll
    for (int r = 0; r < 4; r++) {
      float* erow = out_enc + (size_t)(rowbase + q * 4 + r) * KC + (size_t)(w * 4) * 64 + c0 * 4;
      #pragma unroll
      for (int tt = 0; tt < 4; tt++) {
        float4 ev;
        #pragma unroll
        for (int jj = 0; jj < 4; jj++) {
          float enc = acc[4 * tt + jj][r] * rzv[r];
          (&ev.x)[jj] = enc;
          avg_acc[4 * tt + jj] += enc;
        }
        *reinterpret_cast<float4*>(erow + tt * 64) = ev;
        #pragma unroll
        for (int jj = 0; jj < 4; jj++) {
          float enc = (&ev.x)[jj];
          float pv = __shfl_xor(enc, 1);   // pair (c0,c0+1) -> one dword LDS write
          if (!(lane & 1)) {
            unsigned int pk = (unsigned int)f2bf(enc) | ((unsigned int)f2bf(pv) << 16);
            *reinterpret_cast<unsigned int*>(
                &encT[q * 4 + r][(w * 16 + 4 * tt + jj) * 16 + c0]) = pk;
          }
        }
      }
    }

    // avg_probs in PERMUTED j-space (perplexity is permutation-invariant);
    // lane is the fast index -> 64B-contiguous atomics, one owner per address.
    #pragma unroll
    for (int nt = 0; nt < 16; nt++) {
      float v = avg_acc[nt];
      v += __shfl_xor(v, 16);
      v += __shfl_xor(v, 32);
      if (lane < 16)
        atomicAdd(&avgp_rep[(size_t)(wg & 31) * KC + (w * 16 + nt) * 16 + lane], v);
    }
  }
  __syncthreads();   // ---- encT visible to both waves ----

  // ================= Phase C: quantized = Enc * E (bf16 MFMA) ==================
  f32x4 accq[4];
  #pragma unroll
  for (int n2 = 0; n2 < 4; n2++) accq[n2] = {0.f, 0.f, 0.f, 0.f};
  #pragma unroll
  for (int kb = 0; kb < 16; kb++) {
    s16x8 af = *reinterpret_cast<const s16x8*>(&encT[c0][kb * 32 + q * 8]);
    #pragma unroll
    for (int n2 = 0; n2 < 4; n2++) {
      s16x8 b = *reinterpret_cast<const s16x8*>(
          ETF + ((size_t)((w * 4 + n2) * 16 + kb) * 64 + lane) * 8);
      accq[n2] = __builtin_amdgcn_mfma_f32_16x16x32_bf16(af, b, accq[n2], 0, 0, 0);
    }
  }
  #pragma unroll
  for (int n2 = 0; n2 < 4; n2++) {
    #pragma unroll
    for (int r = 0; r < 4; r++) {
      int grow = rowbase + q * 4 + r;
      out_q[(size_t)grow * DIM + w * 64 + n2 * 16 + c0] = accq[n2][r];
    }
  }
}

// ---- finalize: perplexity + KL scalars
__global__ void finalize_kernel(const float* __restrict__ avgp_rep,
                                const float* __restrict__ kl_rep,
                                float* __restrict__ d_out) {
  __shared__ float red[512];
  int t = threadIdx.x;   // 512
  float s = 0.f;
  for (int rsl = 0; rsl < 32; rsl++) s += avgp_rep[rsl * KC + t];
  float avg = s * (1.0f / (float)N_TOK);
  red[t] = avg * logf(avg + 1e-10f);
  __syncthreads();
  for (int st = 256; st > 0; st >>= 1) { if (t < st) red[t] += red[t + st]; __syncthreads(); }
  if (t == 0) {
    d_out[1 + (size_t)N_TOK * DIM] = __expf(-red[0]);   // perplexity
    float kl = 0.f;
    for (int i2 = 0; i2 < 32; i2++) kl += kl_rep[i2];
    d_out[0] = kl * (1.0f / (float)KC);                 // KL
  }
}

extern "C" void kernel_launch(void* const* d_in, const int* in_sizes, int n_in,
                              void* d_out, int out_size, void* d_ws, size_t ws_size,
                              hipStream_t stream) {
  const float* X = (const float*)d_in[0];
  const float* U = (const float*)d_in[1];
  const float* E = (const float*)d_in[2];
  float* out = (float*)d_out;

  char* ws = (char*)d_ws;
  unsigned short* EF     = (unsigned short*)(ws);            // 512*128*2 = 131072
  unsigned short* ETF    = (unsigned short*)(ws + 131072);   // 128*512*2 = 131072
  float*          normE2 = (float*)(ws + 262144);            // 2048
  float*          avgp_r = (float*)(ws + 264192);            // 32*512*4 = 65536
  float*          kl_r   = (float*)(ws + 329728);            // 128

  hipMemsetAsync(ws + 264192, 0, 65536 + 128, stream);
  prep_kernel<<<512, 128, 0, stream>>>(E, EF, ETF, normE2);
  vq_main<<<N_TOK / 16, 128, 0, stream>>>(X, U, EF, ETF, normE2,
                                          out + 1,
                                          out + 1 + (size_t)N_TOK * DIM + 1,
                                          avgp_r, kl_r);
  finalize_kernel<<<1, 512, 0, stream>>>(avgp_r, kl_r, out);
}